// Round 5
// baseline (1708.701 us; speedup 1.0000x reference)
//
#include <hip/hip_runtime.h>
#include <math.h>

#define NV 20000
#define NV_PAD 20096            // 157 * 128
#define NB 4
#define M_TOTAL (NB * NV_PAD)   // 80384 = 628 * 128
#define CF 64
#define VX 64

typedef short short8 __attribute__((ext_vector_type(8)));
typedef float floatx4 __attribute__((ext_vector_type(4)));

__device__ __forceinline__ float bf2f(unsigned int h) {
  return __uint_as_float(h << 16);
}
__device__ __forceinline__ unsigned short f2bf(float f) {
  unsigned int u = __float_as_uint(f);
  u += 0x7fffu + ((u >> 16) & 1u);   // round-to-nearest-even
  return (unsigned short)(u >> 16);
}

// ---------------- CSR construction (dst-sorted) ----------------

__global__ void hist_dst_kernel(const int* __restrict__ dst, int E, int* __restrict__ cnt) {
  int i = blockIdx.x * blockDim.x + threadIdx.x;
  if (i < E) atomicAdd(&cnt[dst[i]], 1);
}

__global__ void scan_kernel(const int* __restrict__ cnt, int* __restrict__ rowp,
                            float* __restrict__ dinv, int n) {
  __shared__ int sdata[1024];
  __shared__ int run_s;
  if (threadIdx.x == 0) run_s = 0;
  __syncthreads();
  for (int base = 0; base < n; base += 1024) {
    int i = base + (int)threadIdx.x;
    int v = (i < n) ? cnt[i] : 0;
    sdata[threadIdx.x] = v;
    __syncthreads();
    int run = run_s;
    for (int ofs = 1; ofs < 1024; ofs <<= 1) {
      int t = (threadIdx.x >= (unsigned)ofs) ? sdata[threadIdx.x - ofs] : 0;
      __syncthreads();
      sdata[threadIdx.x] += t;
      __syncthreads();
    }
    if (i < n) {
      rowp[i] = run + sdata[threadIdx.x] - v;
      dinv[i] = 1.0f / sqrtf((float)(v + 1));
    }
    if (threadIdx.x == 1023) run_s = run + sdata[1023];
    __syncthreads();
  }
  if (threadIdx.x == 0) rowp[n] = run_s;
}

__global__ void fill_csr_kernel(const int* __restrict__ src, const int* __restrict__ dst, int E,
                                const int* __restrict__ rowp, int* __restrict__ cnt2,
                                const float* __restrict__ dinv,
                                int* __restrict__ esrc, float* __restrict__ dsrc) {
  int i = blockIdx.x * blockDim.x + threadIdx.x;
  if (i < E) {
    int d = dst[i];
    int s = src[i];
    int pos = rowp[d] + atomicAdd(&cnt2[d], 1);
    esrc[pos] = s;
    dsrc[pos] = dinv[s];
  }
}

// dinv replicated per batch with pad rows = 1.0
__global__ void dinvrep_kernel(const float* __restrict__ dinv, float* __restrict__ drep) {
  int idx = blockIdx.x * blockDim.x + threadIdx.x;
  if (idx >= M_TOTAL) return;
  int n = idx % NV_PAD;
  drep[idx] = (n < NV) ? dinv[n] : 1.0f;
}

// ---------------- constant feature sample ----------------
// vn == -1 exactly (batch-min of identical copies), /1.5 -> constant grid point.
__global__ void vfeat_kernel(const float* __restrict__ feat, float* __restrict__ vfeat) {
  int t = blockIdx.x * blockDim.x + threadIdx.x;
  if (t >= NB * CF) return;
  float c = (2.0f * 0.0f / 1e-6f - 1.0f) / 1.5f;
  float pos = (c + 1.0f) * 0.5f * (float)(VX - 1);
  pos = fminf(fmaxf(pos, 0.0f), (float)(VX - 1));
  float f0 = floorf(pos);
  float w = pos - f0;
  int i0 = (int)f0;
  int i1 = i0 + 1; if (i1 > VX - 1) i1 = VX - 1;
  const float* base = feat + (size_t)t * VX * VX * VX;
  float wz[2] = {1.0f - w, w};
  int   iz[2] = {i0, i1};
  float acc = 0.0f;
  #pragma unroll
  for (int a = 0; a < 2; ++a)
    #pragma unroll
    for (int b = 0; b < 2; ++b)
      #pragma unroll
      for (int d = 0; d < 2; ++d)
        acc += wz[a] * wz[b] * wz[d] * base[(size_t)iz[a] * VX * VX + iz[b] * VX + iz[d]];
  vfeat[t] = acc;
}

__global__ void encconst_kernel(const float* __restrict__ vfeat, const float* __restrict__ W1,
                                const float* __restrict__ b1, float* __restrict__ encc) {
  int idx = blockIdx.x * blockDim.x + threadIdx.x;
  if (idx >= NB * 256) return;
  int b = idx >> 8, j = idx & 255;
  float acc = b1[j];
  #pragma unroll 8
  for (int c = 0; c < CF; ++c) acc += vfeat[b * CF + c] * W1[(3 + c) * 256 + j];
  encc[idx] = acc;
}

// x1[row][j] = relu(v[n].W1[0:3][j] + encc[b][j]) -> bf16 ; batched via blockIdx.y
__global__ void enc1_kernel(const float* __restrict__ verts, const float* __restrict__ W1,
                            const float* __restrict__ encc, unsigned short* __restrict__ out) {
  int idx = blockIdx.x * blockDim.x + threadIdx.x;
  if (idx >= NV * 256) return;
  int n = idx >> 8, j = idx & 255;
  int b = blockIdx.y;
  float acc = encc[b * 256 + j]
            + verts[n * 3 + 0] * W1[0 * 256 + j]
            + verts[n * 3 + 1] * W1[1 * 256 + j]
            + verts[n * 3 + 2] * W1[2 * 256 + j];
  out[((size_t)(b * NV_PAD + n)) * 256 + j] = f2bf(fmaxf(acc, 0.0f));
}

// ---------------- combined weight prep (fp32 [K,N] -> bf16 transposed [N,K]) ----------------
struct WPrep {
  const float* src[9];
  unsigned short* dst[9];
};

__global__ void wprep_all_kernel(WPrep wp) {
  const int WKc[9] = {256, 128, 256, 512, 1024, 512, 256, 128, 128};
  const int WNc[9] = {128, 256, 512, 1024, 512, 256, 128, 128, 64};
  const int cum[10] = {0, 32768, 65536, 196608, 720896, 1245184, 1376256, 1409024, 1425408, 1433600};
  int idx = blockIdx.x * blockDim.x + threadIdx.x;
  if (idx >= 1433600) return;
  #pragma unroll
  for (int s = 0; s < 9; ++s) {
    if (idx >= cum[s] && idx < cum[s + 1]) {
      int local = idx - cum[s];
      int k = local / WNc[s];
      int n = local - k * WNc[s];
      wp.dst[s][(size_t)n * WKc[s] + k] = f2bf(wp.src[s][local]);
      return;
    }
  }
}

// ---------------- bf16 MFMA GEMM (BK=64, XOR-swizzled LDS) ----------------
// C[M_TOTAL,N] = A[M_TOTAL,K] @ Bt[N,K]^T ; 128x128 tile, BK=64, 4 waves.
// LDS rows are 64 elems (128 B = full bank span). Slot (row, c) holds global
// 8-elem chunk (c ^ (row&7)); staging pre-swizzles the GLOBAL source address
// (global_load_lds dest must stay linear), fragment reads apply the same XOR.
// XCD-chunked bijective block swizzle (T1/m204) keeps an A M-strip on one XCD.
// launch_bounds(256,5): LDS 32KB/block allows 5 blocks/CU (160KB); VGPR 56
// allows it too — round-1/2's (256,4) capped occupancy at the observed 41%.
// flags: 1=bias, 2=relu, 4=rowscale[m]
#define BM 128
#define BN 128
#define BK 64

__launch_bounds__(256, 5)
__global__ void gemm_bt_kernel(const unsigned short* __restrict__ A,
                               const unsigned short* __restrict__ Bt,
                               const float* __restrict__ bias,
                               const float* __restrict__ rowscale,
                               unsigned short* __restrict__ C,
                               int K, int Nreal, int flags) {
  __shared__ unsigned short As[BM * BK];  // 16 KB, [row][64k]
  __shared__ unsigned short Bs[BN * BK];  // 16 KB
  int tid = threadIdx.x;
  int wave = tid >> 6, lane = tid & 63;

  // XCD-aware chunked remap (bijective for any nwg; m204 variant)
  unsigned int nwg = gridDim.x * gridDim.y;
  unsigned int orig = blockIdx.y * gridDim.x + blockIdx.x;
  unsigned int xcd = orig & 7u, pos = orig >> 3;
  unsigned int q = nwg >> 3, r = nwg & 7u;
  unsigned int wgid = (xcd < r ? xcd * (q + 1u) : r * (q + 1u) + (xcd - r) * q) + pos;
  unsigned int bx = wgid % gridDim.x;
  unsigned int by = wgid / gridDim.x;

  int mbase = by * BM;
  int nbase = bx * BN;
  int wm = (wave >> 1) * 64, wn = (wave & 1) * 64;

  floatx4 acc[4][4] = {};

  // staging: wave w covers rows [w*32, w*32+32), p in [0,4): rows w*32+p*8+(lane>>3)
  // source k-chunk pre-swizzle: (lane&7) ^ (lane>>3)  (row&7 == lane>>3)
  const int rowS = wave * 32 + (lane >> 3);
  const int kseg = (((lane & 7) ^ (lane >> 3)) << 3);       // elems
  const int fr = lane & 15, fq = lane >> 4;                 // fragment row / k-quad
  const int fr7 = fr & 7;

  for (int kb = 0; kb < K; kb += BK) {
    #pragma unroll
    for (int p = 0; p < 4; ++p) {
      const unsigned short* ga = A + (size_t)(mbase + rowS + p * 8) * K + kb + kseg;
      __builtin_amdgcn_global_load_lds(
          (const __attribute__((address_space(1))) void*)ga,
          (__attribute__((address_space(3))) void*)(As + wave * 2048 + p * 512), 16, 0, 0);
      const unsigned short* gb = Bt + (size_t)(nbase + rowS + p * 8) * K + kb + kseg;
      __builtin_amdgcn_global_load_lds(
          (const __attribute__((address_space(1))) void*)gb,
          (__attribute__((address_space(3))) void*)(Bs + wave * 2048 + p * 512), 16, 0, 0);
    }
    __syncthreads();
    #pragma unroll
    for (int kk = 0; kk < 2; ++kk) {
      const int fchunk = (((kk << 2) + fq) ^ fr7) << 3;
      short8 af[4], bf[4];
      #pragma unroll
      for (int i = 0; i < 4; ++i)
        af[i] = *(const short8*)(As + (wm + i * 16 + fr) * BK + fchunk);
      #pragma unroll
      for (int j = 0; j < 4; ++j)
        bf[j] = *(const short8*)(Bs + (wn + j * 16 + fr) * BK + fchunk);
      #pragma unroll
      for (int i = 0; i < 4; ++i)
        #pragma unroll
        for (int j = 0; j < 4; ++j)
          acc[i][j] = __builtin_amdgcn_mfma_f32_16x16x32_bf16(af[i], bf[j], acc[i][j], 0, 0, 0);
    }
    __syncthreads();
  }

  // epilogue: C/D layout col = lane&15, row = (lane>>4)*4 + r
  #pragma unroll
  for (int j = 0; j < 4; ++j) {
    int n = nbase + wn + j * 16 + fr;
    if (n >= Nreal) continue;
    float bv = (flags & 1) ? bias[n] : 0.0f;
    #pragma unroll
    for (int i = 0; i < 4; ++i) {
      #pragma unroll
      for (int r = 0; r < 4; ++r) {
        int m = mbase + wm + i * 16 + fq * 4 + r;
        float v = acc[i][j][r];
        if (flags & 4) v *= rowscale[m];
        v += bv;
        if (flags & 2) v = fmaxf(v, 0.0f);
        C[(size_t)m * Nreal + n] = f2bf(v);
      }
    }
  }
}

// GCN post-aggregate: out[n] = relu(dinv[n] * (hs[n] + sum_src hs[src]) + b), bf16 in/out.
// 8 channels (uint4) per thread; batched via blockIdx.y; lc8 = log2(C/8).
__global__ void gcn_gather_kernel(const uint4* __restrict__ hs8,
                                  const float* __restrict__ bias,
                                  const float* __restrict__ dinv,
                                  const int* __restrict__ rowp, const int* __restrict__ esrc,
                                  uint4* __restrict__ out, int lc8) {
  int idx = blockIdx.x * blockDim.x + threadIdx.x;
  int C8 = 1 << lc8;
  if (idx >= NV * C8) return;
  int n = idx >> lc8;
  int j = idx & (C8 - 1);
  size_t rowbase = (size_t)blockIdx.y * NV_PAD;
  uint4 u = hs8[((rowbase + n) << lc8) + j];
  float a0 = bf2f(u.x & 0xffff), a1 = bf2f(u.x >> 16);
  float a2 = bf2f(u.y & 0xffff), a3 = bf2f(u.y >> 16);
  float a4 = bf2f(u.z & 0xffff), a5 = bf2f(u.z >> 16);
  float a6 = bf2f(u.w & 0xffff), a7 = bf2f(u.w >> 16);
  int s = rowp[n], e = rowp[n + 1];
  int t = s;
  int src = (t < e) ? esrc[t] : 0;
  while (t < e) {
    uint4 v = hs8[((rowbase + src) << lc8) + j];
    ++t;
    int src_n = (t < e) ? esrc[t] : 0;
    a0 += bf2f(v.x & 0xffff); a1 += bf2f(v.x >> 16);
    a2 += bf2f(v.y & 0xffff); a3 += bf2f(v.y >> 16);
    a4 += bf2f(v.z & 0xffff); a5 += bf2f(v.z >> 16);
    a6 += bf2f(v.w & 0xffff); a7 += bf2f(v.w >> 16);
    src = src_n;
  }
  float dn = dinv[n];
  int j8 = j << 3;
  a0 = fmaxf(a0 * dn + bias[j8 + 0], 0.0f);
  a1 = fmaxf(a1 * dn + bias[j8 + 1], 0.0f);
  a2 = fmaxf(a2 * dn + bias[j8 + 2], 0.0f);
  a3 = fmaxf(a3 * dn + bias[j8 + 3], 0.0f);
  a4 = fmaxf(a4 * dn + bias[j8 + 4], 0.0f);
  a5 = fmaxf(a5 * dn + bias[j8 + 5], 0.0f);
  a6 = fmaxf(a6 * dn + bias[j8 + 6], 0.0f);
  a7 = fmaxf(a7 * dn + bias[j8 + 7], 0.0f);
  uint4 o;
  o.x = (unsigned int)f2bf(a0) | ((unsigned int)f2bf(a1) << 16);
  o.y = (unsigned int)f2bf(a2) | ((unsigned int)f2bf(a3) << 16);
  o.z = (unsigned int)f2bf(a4) | ((unsigned int)f2bf(a5) << 16);
  o.w = (unsigned int)f2bf(a6) | ((unsigned int)f2bf(a7) << 16);
  out[((rowbase + n) << lc8) + j] = o;
}

// GCN pre-aggregate (input side): y[n] = dinv[n]*(dinv[n]*x[n] + sum_src dinv[src]*x[src]).
// No bias/relu; bf16 in/out. Used for layers where Cin < Cout: (Nx)@W == N(x@W).
__global__ void gcn_pre_gather_kernel(const uint4* __restrict__ x8,
                                      const float* __restrict__ dinv,
                                      const int* __restrict__ rowp, const int* __restrict__ esrc,
                                      const float* __restrict__ dsrc,
                                      uint4* __restrict__ out, int lc8) {
  int idx = blockIdx.x * blockDim.x + threadIdx.x;
  int C8 = 1 << lc8;
  if (idx >= NV * C8) return;
  int n = idx >> lc8;
  int j = idx & (C8 - 1);
  size_t rowbase = (size_t)blockIdx.y * NV_PAD;
  float dn = dinv[n];
  uint4 u = x8[((rowbase + n) << lc8) + j];
  float a0 = dn * bf2f(u.x & 0xffff), a1 = dn * bf2f(u.x >> 16);
  float a2 = dn * bf2f(u.y & 0xffff), a3 = dn * bf2f(u.y >> 16);
  float a4 = dn * bf2f(u.z & 0xffff), a5 = dn * bf2f(u.z >> 16);
  float a6 = dn * bf2f(u.w & 0xffff), a7 = dn * bf2f(u.w >> 16);
  int s = rowp[n], e = rowp[n + 1];
  int t = s;
  int src = (t < e) ? esrc[t] : 0;
  float w = (t < e) ? dsrc[t] : 0.0f;
  while (t < e) {
    uint4 v = x8[((rowbase + src) << lc8) + j];
    float wv = w;
    ++t;
    src = (t < e) ? esrc[t] : 0;
    w = (t < e) ? dsrc[t] : 0.0f;
    a0 += wv * bf2f(v.x & 0xffff); a1 += wv * bf2f(v.x >> 16);
    a2 += wv * bf2f(v.y & 0xffff); a3 += wv * bf2f(v.y >> 16);
    a4 += wv * bf2f(v.z & 0xffff); a5 += wv * bf2f(v.z >> 16);
    a6 += wv * bf2f(v.w & 0xffff); a7 += wv * bf2f(v.w >> 16);
  }
  a0 *= dn; a1 *= dn; a2 *= dn; a3 *= dn;
  a4 *= dn; a5 *= dn; a6 *= dn; a7 *= dn;
  uint4 o;
  o.x = (unsigned int)f2bf(a0) | ((unsigned int)f2bf(a1) << 16);
  o.y = (unsigned int)f2bf(a2) | ((unsigned int)f2bf(a3) << 16);
  o.z = (unsigned int)f2bf(a4) | ((unsigned int)f2bf(a5) << 16);
  o.w = (unsigned int)f2bf(a6) | ((unsigned int)f2bf(a7) << 16);
  out[((rowbase + n) << lc8) + j] = o;
}

// final head, one thread per vertex per batch; vectorized uint4 row loads (G13)
__global__ void head3_kernel(const unsigned short* __restrict__ d, const float* __restrict__ hW3,
                             const float* __restrict__ hb3, const float* __restrict__ verts,
                             float* __restrict__ out) {
  int n = blockIdx.x * blockDim.x + threadIdx.x;
  if (n >= NV) return;
  int b = blockIdx.y;
  const uint4* drow = (const uint4*)(d + ((size_t)(b * NV_PAD + n)) * 64);
  float a0 = hb3[0], a1 = hb3[1], a2 = hb3[2];
  #pragma unroll
  for (int qv = 0; qv < 8; ++qv) {
    uint4 v = drow[qv];
    float f0 = bf2f(v.x & 0xffff), f1 = bf2f(v.x >> 16);
    float f2 = bf2f(v.y & 0xffff), f3 = bf2f(v.y >> 16);
    float f4 = bf2f(v.z & 0xffff), f5 = bf2f(v.z >> 16);
    float f6 = bf2f(v.w & 0xffff), f7 = bf2f(v.w >> 16);
    const float* w = hW3 + qv * 24;
    a0 += f0 * w[0]  + f1 * w[3]  + f2 * w[6]  + f3 * w[9]
        + f4 * w[12] + f5 * w[15] + f6 * w[18] + f7 * w[21];
    a1 += f0 * w[1]  + f1 * w[4]  + f2 * w[7]  + f3 * w[10]
        + f4 * w[13] + f5 * w[16] + f6 * w[19] + f7 * w[22];
    a2 += f0 * w[2]  + f1 * w[5]  + f2 * w[8]  + f3 * w[11]
        + f4 * w[14] + f5 * w[17] + f6 * w[20] + f7 * w[23];
  }
  float t0 = fminf(fmaxf(tanhf(a0), -2.5f), 2.5f);
  float t1 = fminf(fmaxf(tanhf(a1), -2.5f), 2.5f);
  float t2 = fminf(fmaxf(tanhf(a2), -2.5f), 2.5f);
  size_t ob = (size_t)b * NV * 3 + (size_t)n * 3;
  out[ob + 0] = verts[n * 3 + 0] + t0;
  out[ob + 1] = verts[n * 3 + 1] + t1;
  out[ob + 2] = verts[n * 3 + 2] + t2;
}

// ---------------- launch ----------------

static inline void launch_gemm(const unsigned short* A, const unsigned short* Bt,
                               const float* bias, const float* rowscale, unsigned short* C,
                               int N, int K, int flags, hipStream_t stream) {
  int Npad = (N + BN - 1) / BN * BN;
  dim3 grid(Npad / BN, M_TOTAL / BM);
  gemm_bt_kernel<<<grid, 256, 0, stream>>>(A, Bt, bias, rowscale, C, K, N, flags);
}

extern "C" void kernel_launch(void* const* d_in, const int* in_sizes, int n_in,
                              void* d_out, int out_size, void* d_ws, size_t ws_size,
                              hipStream_t stream) {
  const float* features = (const float*)d_in[0];
  const float* vertices = (const float*)d_in[1];
  const int* edge_index = (const int*)d_in[2];
  const int E = in_sizes[2] / 2;
  const int* esrc_in = edge_index;       // edge_index[0] = src
  const int* edst_in = edge_index + E;   // edge_index[1] = dst
  const float* enc_W1 = (const float*)d_in[3];
  const float* enc_b1 = (const float*)d_in[4];
  const float* enc_W2 = (const float*)d_in[5];
  const float* enc_b2 = (const float*)d_in[6];
  const float* gW[6]; const float* gb[6];
  for (int i = 0; i < 6; ++i) { gW[i] = (const float*)d_in[7 + 2 * i]; gb[i] = (const float*)d_in[8 + 2 * i]; }
  const float* hW1 = (const float*)d_in[19]; const float* hb1 = (const float*)d_in[20];
  const float* hW2 = (const float*)d_in[21]; const float* hb2 = (const float*)d_in[22];
  const float* hW3 = (const float*)d_in[23]; const float* hb3 = (const float*)d_in[24];

  char* ws = (char*)d_ws;
  size_t off = 0;
  auto alloc = [&](size_t bytes) -> void* {
    void* p = (void*)(ws + off);
    off += (bytes + 255) & ~(size_t)255;
    return p;
  };
  unsigned short* bufA = (unsigned short*)alloc((size_t)M_TOTAL * 1024 * 2);
  unsigned short* bufB = (unsigned short*)alloc((size_t)M_TOTAL * 1024 * 2);
  float* dinv  = (float*)alloc(NV * sizeof(float));
  float* drep  = (float*)alloc(M_TOTAL * sizeof(float));
  float* vfeat = (float*)alloc(NB * CF * sizeof(float));
  float* encc  = (float*)alloc(NB * 256 * sizeof(float));
  int* cnt  = (int*)alloc(NV * sizeof(int));
  int* rowp = (int*)alloc((NV + 1) * sizeof(int));
  int* cnt2 = (int*)alloc(NV * sizeof(int));
  int* esrc = (int*)alloc((size_t)E * sizeof(int));
  float* dsrc = (float*)alloc((size_t)E * sizeof(float));
  // bf16 transposed weights (rows padded to >=128)
  const size_t wtsz[9] = {128 * 256, 256 * 128, 512 * 256, 1024 * 512, 512 * 1024,
                          256 * 512, 128 * 256, 128 * 128, 128 * 128};
  unsigned short* wt[9];
  {
    size_t tot = 0;
    for (int i = 0; i < 9; ++i) tot += wtsz[i];
    unsigned short* base = (unsigned short*)alloc(tot * 2);
    size_t o = 0;
    for (int i = 0; i < 9; ++i) { wt[i] = base + o; o += wtsz[i]; }
  }

  hipMemsetAsync(cnt,  0, NV * sizeof(int), stream);
  hipMemsetAsync(cnt2, 0, NV * sizeof(int), stream);
  hist_dst_kernel<<<(E + 255) / 256, 256, 0, stream>>>(edst_in, E, cnt);
  scan_kernel<<<1, 1024, 0, stream>>>(cnt, rowp, dinv, NV);
  fill_csr_kernel<<<(E + 255) / 256, 256, 0, stream>>>(esrc_in, edst_in, E, rowp, cnt2,
                                                       dinv, esrc, dsrc);
  dinvrep_kernel<<<(M_TOTAL + 255) / 256, 256, 0, stream>>>(dinv, drep);
  vfeat_kernel<<<1, 256, 0, stream>>>(features, vfeat);
  encconst_kernel<<<NB, 256, 0, stream>>>(vfeat, enc_W1, enc_b1, encc);

  WPrep wp;
  const float* wsrc[9] = {enc_W2, gW[0], gW[1], gW[2], gW[3], gW[4], gW[5], hW1, hW2};
  for (int i = 0; i < 9; ++i) { wp.src[i] = wsrc[i]; wp.dst[i] = wt[i]; }
  wprep_all_kernel<<<(1433600 + 255) / 256, 256, 0, stream>>>(wp);

  const int gout[6] = {256, 512, 1024, 512, 256, 128};
  const int gin[6]  = {128, 256, 512, 1024, 512, 256};
  const int inlc8[6] = {4, 5, 6, 7, 6, 5};   // log2(Cin/8)
  const int outlc8[6] = {5, 6, 7, 6, 5, 4};  // log2(Cout/8)
  const int inside[6] = {1, 1, 1, 0, 0, 0};  // aggregate on min(Cin, Cout) side

  // enc layer 1 (all batches) -> bufA [M_TOTAL,256]
  dim3 e1grid((NV * 256 + 255) / 256, NB);
  enc1_kernel<<<e1grid, 256, 0, stream>>>(vertices, enc_W1, encc, bufA);
  // enc layer 2 -> bufB [M_TOTAL,128]
  launch_gemm(bufA, wt[0], enc_b2, nullptr, bufB, 128, 256, 1 | 2, stream);

  unsigned short* x = bufB;
  unsigned short* h = bufA;
  for (int i = 0; i < 6; ++i) {
    if (inside[i]) {
      // y = N x  (gather on input, Cin channels), then out = relu(y @ W + b)
      int total8 = NV * (gin[i] / 8);
      dim3 pgrid((total8 + 255) / 256, NB);
      gcn_pre_gather_kernel<<<pgrid, 256, 0, stream>>>(
          (const uint4*)x, dinv, rowp, esrc, dsrc, (uint4*)h, inlc8[i]);
      launch_gemm(h, wt[1 + i], gb[i], nullptr, x, gout[i], gin[i], 1 | 2, stream);
    } else {
      // hs = (x @ gW) * dinv[row], then out = relu(dinv*(hs[n]+sum hs[src]) + b)
      launch_gemm(x, wt[1 + i], nullptr, drep, h, gout[i], gin[i], 4, stream);
      int total8 = NV * (gout[i] / 8);
      dim3 ggrid((total8 + 255) / 256, NB);
      gcn_gather_kernel<<<ggrid, 256, 0, stream>>>(
          (const uint4*)h, gb[i], dinv, rowp, esrc, (uint4*)x, outlc8[i]);
    }
  }
  // head
  launch_gemm(x, wt[7], hb1, nullptr, h, 128, 128, 1 | 2, stream);  // bufA [M_TOTAL,128]
  launch_gemm(h, wt[8], hb2, nullptr, x, 64, 128, 1 | 2, stream);   // bufB [M_TOTAL,64]
  dim3 hgrid((NV + 255) / 256, NB);
  head3_kernel<<<hgrid, 256, 0, stream>>>(x, hW3, hb3, vertices, (float*)d_out);
}

// Round 6
// 1120.755 us; speedup vs baseline: 1.5246x; 1.5246x over previous
//
#include <hip/hip_runtime.h>
#include <math.h>

#define NV 20000
#define NV_PAD 20096            // 157 * 128
#define NB 4
#define M_TOTAL (NB * NV_PAD)   // 80384 = 628 * 128
#define CF 64
#define VX 64

typedef short short8 __attribute__((ext_vector_type(8)));
typedef float floatx4 __attribute__((ext_vector_type(4)));

__device__ __forceinline__ float bf2f(unsigned int h) {
  return __uint_as_float(h << 16);
}
__device__ __forceinline__ unsigned short f2bf(float f) {
  unsigned int u = __float_as_uint(f);
  u += 0x7fffu + ((u >> 16) & 1u);   // round-to-nearest-even
  return (unsigned short)(u >> 16);
}

// ---------------- CSR construction (dst-sorted) ----------------

__global__ void hist_dst_kernel(const int* __restrict__ dst, int E, int* __restrict__ cnt) {
  int i = blockIdx.x * blockDim.x + threadIdx.x;
  if (i < E) atomicAdd(&cnt[dst[i]], 1);
}

__global__ void scan_kernel(const int* __restrict__ cnt, int* __restrict__ rowp,
                            float* __restrict__ dinv, int n) {
  __shared__ int sdata[1024];
  __shared__ int run_s;
  if (threadIdx.x == 0) run_s = 0;
  __syncthreads();
  for (int base = 0; base < n; base += 1024) {
    int i = base + (int)threadIdx.x;
    int v = (i < n) ? cnt[i] : 0;
    sdata[threadIdx.x] = v;
    __syncthreads();
    int run = run_s;
    for (int ofs = 1; ofs < 1024; ofs <<= 1) {
      int t = (threadIdx.x >= (unsigned)ofs) ? sdata[threadIdx.x - ofs] : 0;
      __syncthreads();
      sdata[threadIdx.x] += t;
      __syncthreads();
    }
    if (i < n) {
      rowp[i] = run + sdata[threadIdx.x] - v;
      dinv[i] = 1.0f / sqrtf((float)(v + 1));
    }
    if (threadIdx.x == 1023) run_s = run + sdata[1023];
    __syncthreads();
  }
  if (threadIdx.x == 0) rowp[n] = run_s;
}

__global__ void fill_csr_kernel(const int* __restrict__ src, const int* __restrict__ dst, int E,
                                const int* __restrict__ rowp, int* __restrict__ cnt2,
                                const float* __restrict__ dinv,
                                int* __restrict__ esrc, float* __restrict__ dsrc) {
  int i = blockIdx.x * blockDim.x + threadIdx.x;
  if (i < E) {
    int d = dst[i];
    int s = src[i];
    int pos = rowp[d] + atomicAdd(&cnt2[d], 1);
    esrc[pos] = s;
    dsrc[pos] = dinv[s];
  }
}

// dinv replicated per batch with pad rows = 1.0
__global__ void dinvrep_kernel(const float* __restrict__ dinv, float* __restrict__ drep) {
  int idx = blockIdx.x * blockDim.x + threadIdx.x;
  if (idx >= M_TOTAL) return;
  int n = idx % NV_PAD;
  drep[idx] = (n < NV) ? dinv[n] : 1.0f;
}

// ---------------- constant feature sample ----------------
// vn == -1 exactly (batch-min of identical copies), /1.5 -> constant grid point.
__global__ void vfeat_kernel(const float* __restrict__ feat, float* __restrict__ vfeat) {
  int t = blockIdx.x * blockDim.x + threadIdx.x;
  if (t >= NB * CF) return;
  float c = (2.0f * 0.0f / 1e-6f - 1.0f) / 1.5f;
  float pos = (c + 1.0f) * 0.5f * (float)(VX - 1);
  pos = fminf(fmaxf(pos, 0.0f), (float)(VX - 1));
  float f0 = floorf(pos);
  float w = pos - f0;
  int i0 = (int)f0;
  int i1 = i0 + 1; if (i1 > VX - 1) i1 = VX - 1;
  const float* base = feat + (size_t)t * VX * VX * VX;
  float wz[2] = {1.0f - w, w};
  int   iz[2] = {i0, i1};
  float acc = 0.0f;
  #pragma unroll
  for (int a = 0; a < 2; ++a)
    #pragma unroll
    for (int b = 0; b < 2; ++b)
      #pragma unroll
      for (int d = 0; d < 2; ++d)
        acc += wz[a] * wz[b] * wz[d] * base[(size_t)iz[a] * VX * VX + iz[b] * VX + iz[d]];
  vfeat[t] = acc;
}

__global__ void encconst_kernel(const float* __restrict__ vfeat, const float* __restrict__ W1,
                                const float* __restrict__ b1, float* __restrict__ encc) {
  int idx = blockIdx.x * blockDim.x + threadIdx.x;
  if (idx >= NB * 256) return;
  int b = idx >> 8, j = idx & 255;
  float acc = b1[j];
  #pragma unroll 8
  for (int c = 0; c < CF; ++c) acc += vfeat[b * CF + c] * W1[(3 + c) * 256 + j];
  encc[idx] = acc;
}

// x1[row][j] = relu(v[n].W1[0:3][j] + encc[b][j]) -> bf16 ; batched via blockIdx.y
__global__ void enc1_kernel(const float* __restrict__ verts, const float* __restrict__ W1,
                            const float* __restrict__ encc, unsigned short* __restrict__ out) {
  int idx = blockIdx.x * blockDim.x + threadIdx.x;
  if (idx >= NV * 256) return;
  int n = idx >> 8, j = idx & 255;
  int b = blockIdx.y;
  float acc = encc[b * 256 + j]
            + verts[n * 3 + 0] * W1[0 * 256 + j]
            + verts[n * 3 + 1] * W1[1 * 256 + j]
            + verts[n * 3 + 2] * W1[2 * 256 + j];
  out[((size_t)(b * NV_PAD + n)) * 256 + j] = f2bf(fmaxf(acc, 0.0f));
}

// ---------------- combined weight prep (fp32 [K,N] -> bf16 transposed [N,K]) ----------------
struct WPrep {
  const float* src[9];
  unsigned short* dst[9];
};

__global__ void wprep_all_kernel(WPrep wp) {
  const int WKc[9] = {256, 128, 256, 512, 1024, 512, 256, 128, 128};
  const int WNc[9] = {128, 256, 512, 1024, 512, 256, 128, 128, 64};
  const int cum[10] = {0, 32768, 65536, 196608, 720896, 1245184, 1376256, 1409024, 1425408, 1433600};
  int idx = blockIdx.x * blockDim.x + threadIdx.x;
  if (idx >= 1433600) return;
  #pragma unroll
  for (int s = 0; s < 9; ++s) {
    if (idx >= cum[s] && idx < cum[s + 1]) {
      int local = idx - cum[s];
      int k = local / WNc[s];
      int n = local - k * WNc[s];
      wp.dst[s][(size_t)n * WKc[s] + k] = f2bf(wp.src[s][local]);
      return;
    }
  }
}

// ---------------- bf16 MFMA GEMM (BK=64, XOR-swizzled LDS) ----------------
// C[M_TOTAL,N] = A[M_TOTAL,K] @ Bt[N,K]^T ; 128x128 tile, BK=64, 4 waves.
// LDS rows are 64 elems (128 B = full bank span). Slot (row, c) holds global
// 8-elem chunk (c ^ (row&7)); staging pre-swizzles the GLOBAL source address
// (global_load_lds dest must stay linear), fragment reads apply the same XOR.
// XCD-chunked bijective block swizzle (T1/m204) keeps an A M-strip on one XCD.
// launch_bounds MUST stay (256,4): (256,5) cuts the per-wave reg budget to ~96
// < the ~120 needed (64 AGPR acc + ~56 VGPR) -> acc spills to scratch
// (round-4: WRITE_SIZE 230->719 MB, MfmaUtil 17->9%, 157->368 us).
// flags: 1=bias, 2=relu, 4=rowscale[m]
#define BM 128
#define BN 128
#define BK 64

__launch_bounds__(256, 4)
__global__ void gemm_bt_kernel(const unsigned short* __restrict__ A,
                               const unsigned short* __restrict__ Bt,
                               const float* __restrict__ bias,
                               const float* __restrict__ rowscale,
                               unsigned short* __restrict__ C,
                               int K, int Nreal, int flags) {
  __shared__ unsigned short As[BM * BK];  // 16 KB, [row][64k]
  __shared__ unsigned short Bs[BN * BK];  // 16 KB
  int tid = threadIdx.x;
  int wave = tid >> 6, lane = tid & 63;

  // XCD-aware chunked remap (bijective for any nwg; m204 variant)
  unsigned int nwg = gridDim.x * gridDim.y;
  unsigned int orig = blockIdx.y * gridDim.x + blockIdx.x;
  unsigned int xcd = orig & 7u, pos = orig >> 3;
  unsigned int q = nwg >> 3, r = nwg & 7u;
  unsigned int wgid = (xcd < r ? xcd * (q + 1u) : r * (q + 1u) + (xcd - r) * q) + pos;
  unsigned int bx = wgid % gridDim.x;
  unsigned int by = wgid / gridDim.x;

  int mbase = by * BM;
  int nbase = bx * BN;
  int wm = (wave >> 1) * 64, wn = (wave & 1) * 64;

  floatx4 acc[4][4] = {};

  // staging: wave w covers rows [w*32, w*32+32), p in [0,4): rows w*32+p*8+(lane>>3)
  // source k-chunk pre-swizzle: (lane&7) ^ (lane>>3)  (row&7 == lane>>3)
  const int rowS = wave * 32 + (lane >> 3);
  const int kseg = (((lane & 7) ^ (lane >> 3)) << 3);       // elems
  const int fr = lane & 15, fq = lane >> 4;                 // fragment row / k-quad
  const int fr7 = fr & 7;

  for (int kb = 0; kb < K; kb += BK) {
    #pragma unroll
    for (int p = 0; p < 4; ++p) {
      const unsigned short* ga = A + (size_t)(mbase + rowS + p * 8) * K + kb + kseg;
      __builtin_amdgcn_global_load_lds(
          (const __attribute__((address_space(1))) void*)ga,
          (__attribute__((address_space(3))) void*)(As + wave * 2048 + p * 512), 16, 0, 0);
      const unsigned short* gb = Bt + (size_t)(nbase + rowS + p * 8) * K + kb + kseg;
      __builtin_amdgcn_global_load_lds(
          (const __attribute__((address_space(1))) void*)gb,
          (__attribute__((address_space(3))) void*)(Bs + wave * 2048 + p * 512), 16, 0, 0);
    }
    __syncthreads();
    #pragma unroll
    for (int kk = 0; kk < 2; ++kk) {
      const int fchunk = (((kk << 2) + fq) ^ fr7) << 3;
      short8 af[4], bf[4];
      #pragma unroll
      for (int i = 0; i < 4; ++i)
        af[i] = *(const short8*)(As + (wm + i * 16 + fr) * BK + fchunk);
      #pragma unroll
      for (int j = 0; j < 4; ++j)
        bf[j] = *(const short8*)(Bs + (wn + j * 16 + fr) * BK + fchunk);
      #pragma unroll
      for (int i = 0; i < 4; ++i)
        #pragma unroll
        for (int j = 0; j < 4; ++j)
          acc[i][j] = __builtin_amdgcn_mfma_f32_16x16x32_bf16(af[i], bf[j], acc[i][j], 0, 0, 0);
    }
    __syncthreads();
  }

  // epilogue: C/D layout col = lane&15, row = (lane>>4)*4 + r
  #pragma unroll
  for (int j = 0; j < 4; ++j) {
    int n = nbase + wn + j * 16 + fr;
    if (n >= Nreal) continue;
    float bv = (flags & 1) ? bias[n] : 0.0f;
    #pragma unroll
    for (int i = 0; i < 4; ++i) {
      #pragma unroll
      for (int r = 0; r < 4; ++r) {
        int m = mbase + wm + i * 16 + fq * 4 + r;
        float v = acc[i][j][r];
        if (flags & 4) v *= rowscale[m];
        v += bv;
        if (flags & 2) v = fmaxf(v, 0.0f);
        C[(size_t)m * Nreal + n] = f2bf(v);
      }
    }
  }
}

// GCN post-aggregate: out[n] = relu(dinv[n] * (hs[n] + sum_src hs[src]) + b), bf16 in/out.
// 8 channels (uint4) per thread; batched via blockIdx.y; lc8 = log2(C/8).
__global__ void gcn_gather_kernel(const uint4* __restrict__ hs8,
                                  const float* __restrict__ bias,
                                  const float* __restrict__ dinv,
                                  const int* __restrict__ rowp, const int* __restrict__ esrc,
                                  uint4* __restrict__ out, int lc8) {
  int idx = blockIdx.x * blockDim.x + threadIdx.x;
  int C8 = 1 << lc8;
  if (idx >= NV * C8) return;
  int n = idx >> lc8;
  int j = idx & (C8 - 1);
  size_t rowbase = (size_t)blockIdx.y * NV_PAD;
  uint4 u = hs8[((rowbase + n) << lc8) + j];
  float a0 = bf2f(u.x & 0xffff), a1 = bf2f(u.x >> 16);
  float a2 = bf2f(u.y & 0xffff), a3 = bf2f(u.y >> 16);
  float a4 = bf2f(u.z & 0xffff), a5 = bf2f(u.z >> 16);
  float a6 = bf2f(u.w & 0xffff), a7 = bf2f(u.w >> 16);
  int s = rowp[n], e = rowp[n + 1];
  int t = s;
  int src = (t < e) ? esrc[t] : 0;
  while (t < e) {
    uint4 v = hs8[((rowbase + src) << lc8) + j];
    ++t;
    int src_n = (t < e) ? esrc[t] : 0;
    a0 += bf2f(v.x & 0xffff); a1 += bf2f(v.x >> 16);
    a2 += bf2f(v.y & 0xffff); a3 += bf2f(v.y >> 16);
    a4 += bf2f(v.z & 0xffff); a5 += bf2f(v.z >> 16);
    a6 += bf2f(v.w & 0xffff); a7 += bf2f(v.w >> 16);
    src = src_n;
  }
  float dn = dinv[n];
  int j8 = j << 3;
  a0 = fmaxf(a0 * dn + bias[j8 + 0], 0.0f);
  a1 = fmaxf(a1 * dn + bias[j8 + 1], 0.0f);
  a2 = fmaxf(a2 * dn + bias[j8 + 2], 0.0f);
  a3 = fmaxf(a3 * dn + bias[j8 + 3], 0.0f);
  a4 = fmaxf(a4 * dn + bias[j8 + 4], 0.0f);
  a5 = fmaxf(a5 * dn + bias[j8 + 5], 0.0f);
  a6 = fmaxf(a6 * dn + bias[j8 + 6], 0.0f);
  a7 = fmaxf(a7 * dn + bias[j8 + 7], 0.0f);
  uint4 o;
  o.x = (unsigned int)f2bf(a0) | ((unsigned int)f2bf(a1) << 16);
  o.y = (unsigned int)f2bf(a2) | ((unsigned int)f2bf(a3) << 16);
  o.z = (unsigned int)f2bf(a4) | ((unsigned int)f2bf(a5) << 16);
  o.w = (unsigned int)f2bf(a6) | ((unsigned int)f2bf(a7) << 16);
  out[((rowbase + n) << lc8) + j] = o;
}

// GCN pre-aggregate (input side): y[n] = dinv[n]*(dinv[n]*x[n] + sum_src dinv[src]*x[src]).
// No bias/relu; bf16 in/out. Used for layers where Cin < Cout: (Nx)@W == N(x@W).
__global__ void gcn_pre_gather_kernel(const uint4* __restrict__ x8,
                                      const float* __restrict__ dinv,
                                      const int* __restrict__ rowp, const int* __restrict__ esrc,
                                      const float* __restrict__ dsrc,
                                      uint4* __restrict__ out, int lc8) {
  int idx = blockIdx.x * blockDim.x + threadIdx.x;
  int C8 = 1 << lc8;
  if (idx >= NV * C8) return;
  int n = idx >> lc8;
  int j = idx & (C8 - 1);
  size_t rowbase = (size_t)blockIdx.y * NV_PAD;
  float dn = dinv[n];
  uint4 u = x8[((rowbase + n) << lc8) + j];
  float a0 = dn * bf2f(u.x & 0xffff), a1 = dn * bf2f(u.x >> 16);
  float a2 = dn * bf2f(u.y & 0xffff), a3 = dn * bf2f(u.y >> 16);
  float a4 = dn * bf2f(u.z & 0xffff), a5 = dn * bf2f(u.z >> 16);
  float a6 = dn * bf2f(u.w & 0xffff), a7 = dn * bf2f(u.w >> 16);
  int s = rowp[n], e = rowp[n + 1];
  int t = s;
  int src = (t < e) ? esrc[t] : 0;
  float w = (t < e) ? dsrc[t] : 0.0f;
  while (t < e) {
    uint4 v = x8[((rowbase + src) << lc8) + j];
    float wv = w;
    ++t;
    src = (t < e) ? esrc[t] : 0;
    w = (t < e) ? dsrc[t] : 0.0f;
    a0 += wv * bf2f(v.x & 0xffff); a1 += wv * bf2f(v.x >> 16);
    a2 += wv * bf2f(v.y & 0xffff); a3 += wv * bf2f(v.y >> 16);
    a4 += wv * bf2f(v.z & 0xffff); a5 += wv * bf2f(v.z >> 16);
    a6 += wv * bf2f(v.w & 0xffff); a7 += wv * bf2f(v.w >> 16);
  }
  a0 *= dn; a1 *= dn; a2 *= dn; a3 *= dn;
  a4 *= dn; a5 *= dn; a6 *= dn; a7 *= dn;
  uint4 o;
  o.x = (unsigned int)f2bf(a0) | ((unsigned int)f2bf(a1) << 16);
  o.y = (unsigned int)f2bf(a2) | ((unsigned int)f2bf(a3) << 16);
  o.z = (unsigned int)f2bf(a4) | ((unsigned int)f2bf(a5) << 16);
  o.w = (unsigned int)f2bf(a6) | ((unsigned int)f2bf(a7) << 16);
  out[((rowbase + n) << lc8) + j] = o;
}

// final head, one thread per vertex per batch; vectorized uint4 row loads (G13)
__global__ void head3_kernel(const unsigned short* __restrict__ d, const float* __restrict__ hW3,
                             const float* __restrict__ hb3, const float* __restrict__ verts,
                             float* __restrict__ out) {
  int n = blockIdx.x * blockDim.x + threadIdx.x;
  if (n >= NV) return;
  int b = blockIdx.y;
  const uint4* drow = (const uint4*)(d + ((size_t)(b * NV_PAD + n)) * 64);
  float a0 = hb3[0], a1 = hb3[1], a2 = hb3[2];
  #pragma unroll
  for (int qv = 0; qv < 8; ++qv) {
    uint4 v = drow[qv];
    float f0 = bf2f(v.x & 0xffff), f1 = bf2f(v.x >> 16);
    float f2 = bf2f(v.y & 0xffff), f3 = bf2f(v.y >> 16);
    float f4 = bf2f(v.z & 0xffff), f5 = bf2f(v.z >> 16);
    float f6 = bf2f(v.w & 0xffff), f7 = bf2f(v.w >> 16);
    const float* w = hW3 + qv * 24;
    a0 += f0 * w[0]  + f1 * w[3]  + f2 * w[6]  + f3 * w[9]
        + f4 * w[12] + f5 * w[15] + f6 * w[18] + f7 * w[21];
    a1 += f0 * w[1]  + f1 * w[4]  + f2 * w[7]  + f3 * w[10]
        + f4 * w[13] + f5 * w[16] + f6 * w[19] + f7 * w[22];
    a2 += f0 * w[2]  + f1 * w[5]  + f2 * w[8]  + f3 * w[11]
        + f4 * w[14] + f5 * w[17] + f6 * w[20] + f7 * w[23];
  }
  float t0 = fminf(fmaxf(tanhf(a0), -2.5f), 2.5f);
  float t1 = fminf(fmaxf(tanhf(a1), -2.5f), 2.5f);
  float t2 = fminf(fmaxf(tanhf(a2), -2.5f), 2.5f);
  size_t ob = (size_t)b * NV * 3 + (size_t)n * 3;
  out[ob + 0] = verts[n * 3 + 0] + t0;
  out[ob + 1] = verts[n * 3 + 1] + t1;
  out[ob + 2] = verts[n * 3 + 2] + t2;
}

// ---------------- launch ----------------

static inline void launch_gemm(const unsigned short* A, const unsigned short* Bt,
                               const float* bias, const float* rowscale, unsigned short* C,
                               int N, int K, int flags, hipStream_t stream) {
  int Npad = (N + BN - 1) / BN * BN;
  dim3 grid(Npad / BN, M_TOTAL / BM);
  gemm_bt_kernel<<<grid, 256, 0, stream>>>(A, Bt, bias, rowscale, C, K, N, flags);
}

extern "C" void kernel_launch(void* const* d_in, const int* in_sizes, int n_in,
                              void* d_out, int out_size, void* d_ws, size_t ws_size,
                              hipStream_t stream) {
  const float* features = (const float*)d_in[0];
  const float* vertices = (const float*)d_in[1];
  const int* edge_index = (const int*)d_in[2];
  const int E = in_sizes[2] / 2;
  const int* esrc_in = edge_index;       // edge_index[0] = src
  const int* edst_in = edge_index + E;   // edge_index[1] = dst
  const float* enc_W1 = (const float*)d_in[3];
  const float* enc_b1 = (const float*)d_in[4];
  const float* enc_W2 = (const float*)d_in[5];
  const float* enc_b2 = (const float*)d_in[6];
  const float* gW[6]; const float* gb[6];
  for (int i = 0; i < 6; ++i) { gW[i] = (const float*)d_in[7 + 2 * i]; gb[i] = (const float*)d_in[8 + 2 * i]; }
  const float* hW1 = (const float*)d_in[19]; const float* hb1 = (const float*)d_in[20];
  const float* hW2 = (const float*)d_in[21]; const float* hb2 = (const float*)d_in[22];
  const float* hW3 = (const float*)d_in[23]; const float* hb3 = (const float*)d_in[24];

  char* ws = (char*)d_ws;
  size_t off = 0;
  auto alloc = [&](size_t bytes) -> void* {
    void* p = (void*)(ws + off);
    off += (bytes + 255) & ~(size_t)255;
    return p;
  };
  unsigned short* bufA = (unsigned short*)alloc((size_t)M_TOTAL * 1024 * 2);
  unsigned short* bufB = (unsigned short*)alloc((size_t)M_TOTAL * 1024 * 2);
  float* dinv  = (float*)alloc(NV * sizeof(float));
  float* drep  = (float*)alloc(M_TOTAL * sizeof(float));
  float* vfeat = (float*)alloc(NB * CF * sizeof(float));
  float* encc  = (float*)alloc(NB * 256 * sizeof(float));
  int* cnt  = (int*)alloc(NV * sizeof(int));
  int* rowp = (int*)alloc((NV + 1) * sizeof(int));
  int* cnt2 = (int*)alloc(NV * sizeof(int));
  int* esrc = (int*)alloc((size_t)E * sizeof(int));
  float* dsrc = (float*)alloc((size_t)E * sizeof(float));
  // bf16 transposed weights (rows padded to >=128)
  const size_t wtsz[9] = {128 * 256, 256 * 128, 512 * 256, 1024 * 512, 512 * 1024,
                          256 * 512, 128 * 256, 128 * 128, 128 * 128};
  unsigned short* wt[9];
  {
    size_t tot = 0;
    for (int i = 0; i < 9; ++i) tot += wtsz[i];
    unsigned short* base = (unsigned short*)alloc(tot * 2);
    size_t o = 0;
    for (int i = 0; i < 9; ++i) { wt[i] = base + o; o += wtsz[i]; }
  }

  hipMemsetAsync(cnt,  0, NV * sizeof(int), stream);
  hipMemsetAsync(cnt2, 0, NV * sizeof(int), stream);
  hist_dst_kernel<<<(E + 255) / 256, 256, 0, stream>>>(edst_in, E, cnt);
  scan_kernel<<<1, 1024, 0, stream>>>(cnt, rowp, dinv, NV);
  fill_csr_kernel<<<(E + 255) / 256, 256, 0, stream>>>(esrc_in, edst_in, E, rowp, cnt2,
                                                       dinv, esrc, dsrc);
  dinvrep_kernel<<<(M_TOTAL + 255) / 256, 256, 0, stream>>>(dinv, drep);
  vfeat_kernel<<<1, 256, 0, stream>>>(features, vfeat);
  encconst_kernel<<<NB, 256, 0, stream>>>(vfeat, enc_W1, enc_b1, encc);

  WPrep wp;
  const float* wsrc[9] = {enc_W2, gW[0], gW[1], gW[2], gW[3], gW[4], gW[5], hW1, hW2};
  for (int i = 0; i < 9; ++i) { wp.src[i] = wsrc[i]; wp.dst[i] = wt[i]; }
  wprep_all_kernel<<<(1433600 + 255) / 256, 256, 0, stream>>>(wp);

  const int gout[6] = {256, 512, 1024, 512, 256, 128};
  const int gin[6]  = {128, 256, 512, 1024, 512, 256};
  const int inlc8[6] = {4, 5, 6, 7, 6, 5};   // log2(Cin/8)
  const int outlc8[6] = {5, 6, 7, 6, 5, 4};  // log2(Cout/8)
  const int inside[6] = {1, 1, 1, 0, 0, 0};  // aggregate on min(Cin, Cout) side

  // enc layer 1 (all batches) -> bufA [M_TOTAL,256]
  dim3 e1grid((NV * 256 + 255) / 256, NB);
  enc1_kernel<<<e1grid, 256, 0, stream>>>(vertices, enc_W1, encc, bufA);
  // enc layer 2 -> bufB [M_TOTAL,128]
  launch_gemm(bufA, wt[0], enc_b2, nullptr, bufB, 128, 256, 1 | 2, stream);

  unsigned short* x = bufB;
  unsigned short* h = bufA;
  for (int i = 0; i < 6; ++i) {
    if (inside[i]) {
      // y = N x  (gather on input, Cin channels), then out = relu(y @ W + b)
      int total8 = NV * (gin[i] / 8);
      dim3 pgrid((total8 + 255) / 256, NB);
      gcn_pre_gather_kernel<<<pgrid, 256, 0, stream>>>(
          (const uint4*)x, dinv, rowp, esrc, dsrc, (uint4*)h, inlc8[i]);
      launch_gemm(h, wt[1 + i], gb[i], nullptr, x, gout[i], gin[i], 1 | 2, stream);
    } else {
      // hs = (x @ gW) * dinv[row], then out = relu(dinv*(hs[n]+sum hs[src]) + b)
      launch_gemm(x, wt[1 + i], nullptr, drep, h, gout[i], gin[i], 4, stream);
      int total8 = NV * (gout[i] / 8);
      dim3 ggrid((total8 + 255) / 256, NB);
      gcn_gather_kernel<<<ggrid, 256, 0, stream>>>(
          (const uint4*)h, gb[i], dinv, rowp, esrc, (uint4*)x, outlc8[i]);
    }
  }
  // head
  launch_gemm(x, wt[7], hb1, nullptr, h, 128, 128, 1 | 2, stream);  // bufA [M_TOTAL,128]
  launch_gemm(h, wt[8], hb2, nullptr, x, 64, 128, 1 | 2, stream);   // bufB [M_TOTAL,64]
  dim3 hgrid((NV + 255) / 256, NB);
  head3_kernel<<<hgrid, 256, 0, stream>>>(x, hW3, hb3, vertices, (float*)d_out);
}